// Round 3
// baseline (3712.492 us; speedup 1.0000x reference)
//
// CaptionDecoder on MI355X — round 3: persistent cooperative loop kernel.
// T=32 recurrence in ONE kernel (256 blocks co-resident, custom agent-scope
// barriers); weight-stationary LSTM gates in LDS; bf16x3 MFMA logits GEMM.
#include <hip/hip_runtime.h>

#define E 512
#define H 512
#define V 32000
#define B 32
#define P 196
#define T 32
#define NB 256
#define NT 512

typedef __attribute__((ext_vector_type(8))) short s8v;    // 8 bf16
typedef __attribute__((ext_vector_type(4))) float f4v;    // 4 f32 acc

__device__ __forceinline__ float bf16_to_f(unsigned short u){
  return __uint_as_float(((unsigned)u) << 16);
}
__device__ __forceinline__ unsigned short f_to_bf16(float f){
  unsigned u = __float_as_uint(f);
  u += 0x7FFFu + ((u >> 16) & 1u);   // RNE
  return (unsigned short)(u >> 16);
}
__device__ __forceinline__ float fast_tanh(float x){
  float e = __expf(2.0f*x);
  return 1.0f - 2.0f/(e + 1.0f);
}
__device__ __forceinline__ float sigmoidf_(float x){
  return 1.0f/(1.0f + __expf(-x));
}
__device__ __forceinline__ void load_lds16(const unsigned short* g, unsigned short* l){
  __builtin_amdgcn_global_load_lds(
      (const __attribute__((address_space(1))) void*)g,
      (__attribute__((address_space(3))) void*)l, 16, 0, 0);
}
__device__ __forceinline__ float dot4(float4 a, float4 b){
  return a.x*b.x + a.y*b.y + a.z*b.z + a.w*b.w;
}

#define AT_SCOPE __HIP_MEMORY_SCOPE_AGENT
// Monotonic-counter barrier: idx-th barrier (idx starts at 1) among nb blocks.
__device__ __forceinline__ void bar_arrive_wait(unsigned* cnt, unsigned* gen,
                                                unsigned nb, unsigned idx){
  __syncthreads();
  if (threadIdx.x == 0){
    unsigned old = __hip_atomic_fetch_add(cnt, 1u, __ATOMIC_ACQ_REL, AT_SCOPE);
    if (old == nb*idx - 1u){
      __hip_atomic_store(gen, idx, __ATOMIC_RELEASE, AT_SCOPE);
    } else {
      while (__hip_atomic_load(gen, __ATOMIC_ACQUIRE, AT_SCOPE) < idx)
        __builtin_amdgcn_s_sleep(1);
    }
  }
  __syncthreads();
}

// ---------------------------------------------------------------------------
// f32 (strided) -> bf16 hi (+ optional lo residual). cols==512.
__global__ void split_kernel(const float* __restrict__ src, int src_ld, int src_coff,
                             int rows,
                             unsigned short* __restrict__ dhi, unsigned short* __restrict__ dlo,
                             int dst_ld, int dst_coff)
{
  int n = rows << 9;
  for (int i = blockIdx.x*blockDim.x + threadIdx.x; i < n; i += gridDim.x*blockDim.x){
    int r = i >> 9, c = i & 511;
    float x = src[(size_t)r*src_ld + src_coff + c];
    unsigned short h = f_to_bf16(x);
    dhi[(size_t)r*dst_ld + dst_coff + c] = h;
    if (dlo) dlo[(size_t)r*dst_ld + dst_coff + c] = f_to_bf16(x - bf16_to_f(h));
  }
}

// Embedding gather -> f32, row = b*T+t
__global__ void embed_kernel(const int* __restrict__ caps, const float* __restrict__ embW,
                             float* __restrict__ emb)
{
  int row = blockIdx.x;
  int cap = caps[row];
  const float4* s = (const float4*)(embW + (size_t)cap*E);
  float4* d = (float4*)(emb + (size_t)row*E);
  for (int e = threadIdx.x; e < E/4; e += blockDim.x) d[e] = s[e];
}

// mean over P, then h0/c0 = mean@W^T + b
__global__ __launch_bounds__(512) void prep_kernel(
    const float* __restrict__ feats,
    const float* __restrict__ inith_W, const float* __restrict__ inith_b,
    const float* __restrict__ initc_W, const float* __restrict__ initc_b,
    float* __restrict__ h_state, float* __restrict__ c_state)
{
  __shared__ float mf[E];
  const int b = blockIdx.x, tid = threadIdx.x;
  const float* fb = feats + (size_t)b*P*E + tid;
  float s = 0.f;
  for (int p = 0; p < P; ++p) s += fb[(size_t)p*E];
  mf[tid] = s * (1.0f/196.0f);
  __syncthreads();
  const float* wh = inith_W + (size_t)tid*E;
  const float* wc = initc_W + (size_t)tid*E;
  float h0 = inith_b[tid], c0 = initc_b[tid];
  #pragma unroll 4
  for (int e = 0; e < E; e += 4){
    float4 a4 = *(const float4*)(wh + e);
    float4 b4 = *(const float4*)(wc + e);
    float4 m4 = *(const float4*)(mf + e);
    h0 += dot4(a4, m4);
    c0 += dot4(b4, m4);
  }
  h_state[b*H + tid] = h0;
  c_state[b*H + tid] = c0;
}

// ---------------------------------------------------------------------------
// m97-style bf16 GEMM: C = sum_passes A_p (MxK) * B_p(NxK)^T [+bias]
__global__ __launch_bounds__(256) void gemm_bt_kernel(
    const unsigned short* __restrict__ A0, const unsigned short* __restrict__ A1,
    const unsigned short* __restrict__ A2,
    const unsigned short* __restrict__ B0, const unsigned short* __restrict__ B1,
    const unsigned short* __restrict__ B2,
    float* __restrict__ Cc, const float* __restrict__ bias,
    int N, int K, int npasses, int mt, int swz)
{
  __shared__ __align__(16) unsigned short Al[128*32];
  __shared__ __align__(16) unsigned short Bl[128*32];
  const int tid = threadIdx.x;
  const int wid = tid >> 6, l = tid & 63;
  int f = blockIdx.x;
  if (swz) f = (f & 7)*((int)gridDim.x >> 3) + (f >> 3);
  const int m0 = (f % mt)*128, n0 = (f / mt)*128;
  const int wr = wid >> 1, wc = wid & 1;

  f4v acc[4][4];
  #pragma unroll
  for (int i = 0; i < 4; ++i)
    #pragma unroll
    for (int j = 0; j < 4; ++j) acc[i][j] = (f4v){0.f,0.f,0.f,0.f};

  const int s0 = tid, s1 = tid + 256;
  const int r0 = s0 >> 2, g0 = (s0 & 3) ^ ((r0 >> 1) & 3);
  const int r1 = s1 >> 2, g1 = (s1 & 3) ^ ((r1 >> 1) & 3);
  const int la = l & 15, ch = l >> 4;

  for (int pass = 0; pass < npasses; ++pass){
    const unsigned short* Ap = pass == 0 ? A0 : (pass == 1 ? A1 : A2);
    const unsigned short* Bp = pass == 0 ? B0 : (pass == 1 ? B1 : B2);
    for (int k0 = 0; k0 < K; k0 += 32){
      __syncthreads();
      load_lds16(Ap + (size_t)(m0 + r0)*K + k0 + g0*8, Al + s0*8);
      load_lds16(Ap + (size_t)(m0 + r1)*K + k0 + g1*8, Al + s1*8);
      load_lds16(Bp + (size_t)(n0 + r0)*K + k0 + g0*8, Bl + s0*8);
      load_lds16(Bp + (size_t)(n0 + r1)*K + k0 + g1*8, Bl + s1*8);
      __syncthreads();
      s8v av[4], bv[4];
      #pragma unroll
      for (int mi = 0; mi < 4; ++mi){
        int row = wr*64 + mi*16 + la;
        int cs = ch ^ ((row >> 1) & 3);
        av[mi] = *(const s8v*)(Al + (row*4 + cs)*8);
      }
      #pragma unroll
      for (int ni = 0; ni < 4; ++ni){
        int row = wc*64 + ni*16 + la;
        int cs = ch ^ ((row >> 1) & 3);
        bv[ni] = *(const s8v*)(Bl + (row*4 + cs)*8);
      }
      #pragma unroll
      for (int mi = 0; mi < 4; ++mi)
        #pragma unroll
        for (int ni = 0; ni < 4; ++ni)
          acc[mi][ni] = __builtin_amdgcn_mfma_f32_16x16x32_bf16(av[mi], bv[ni], acc[mi][ni], 0, 0, 0);
    }
  }
  #pragma unroll
  for (int mi = 0; mi < 4; ++mi){
    int row = m0 + wr*64 + mi*16 + (l >> 4)*4;
    #pragma unroll
    for (int ni = 0; ni < 4; ++ni){
      int col = n0 + wc*64 + ni*16 + (l & 15);
      float bb = bias ? bias[col] : 0.0f;
      #pragma unroll
      for (int r = 0; r < 4; ++r)
        Cc[(size_t)(row + r)*N + col] = acc[mi][ni][r] + bb;
    }
  }
}

// ---------------------------------------------------------------------------
// Persistent loop kernel: the whole T=32 recurrence.
// blk -> (b = blk>>3, sub = blk&7) for phases A/B/C; blk owns j-pair {2blk,2blk+1}
// (all 4 gates) for phase D with its Wcat slice parked in LDS.
__global__ __launch_bounds__(512) void loop_kernel(
    const float* __restrict__ feats, const float* __restrict__ feat_proj,
    const float* __restrict__ attn_W, const float* __restrict__ attn_b,
    const float* __restrict__ v_w, const float* __restrict__ emb,
    const float* __restrict__ W_ih, const float* __restrict__ W_hh,
    const float* __restrict__ b_ih, const float* __restrict__ b_hh,
    float* __restrict__ hbuf0, float* __restrict__ hbuf1,
    float* __restrict__ c_state,
    float* __restrict__ hWh_g, float* __restrict__ sc_g, float* __restrict__ ctx_g,
    unsigned short* __restrict__ hall_h, unsigned short* __restrict__ hall_l,
    unsigned* bars)
{
  __shared__ float Wl[8][1540];          // 49.3KB: rows c=g*2+jj -> [Wih 0:1024 | Whh 0:512]
  __shared__ float vws[512];
  __shared__ float bias8[8];
  __shared__ __align__(16) float scr[1024];

  const int blk = blockIdx.x, tid = threadIdx.x;
  const int b = blk >> 3, sub = blk & 7;
  const int jb = blk*2;

  // ---- prologue: park weights in LDS (step-invariant) ----
  #pragma unroll
  for (int r = 0; r < 8; ++r){
    const int col = (r >> 1)*512 + jb + (r & 1);
    const float4* wi = (const float4*)(W_ih + (size_t)col*1024);
    const float4* wh = (const float4*)(W_hh + (size_t)col*512);
    float4* d0 = (float4*)&Wl[r][0];
    float4* d1 = (float4*)&Wl[r][1024];
    for (int q = tid; q < 256; q += NT) d0[q] = wi[q];
    for (int q = tid; q < 128; q += NT) d1[q] = wh[q];
  }
  for (int q = tid; q < 512; q += NT) vws[q] = v_w[q];
  if (tid < 8){
    const int col = (tid >> 1)*512 + jb + (tid & 1);
    bias8[tid] = b_ih[col] + b_hh[col];
  }
  __syncthreads();

  unsigned gi = 0, mi = 0;
  unsigned* gcnt = bars;
  unsigned* ggen = bars + 16;
  unsigned* mcnt = bars + 32 + b*16;
  unsigned* mgen = bars + 32 + 512 + b*16;

  for (int t = 0; t < T; ++t){
    const float* h_in = (t & 1) ? hbuf1 : hbuf0;
    float*       h_out= (t & 1) ? hbuf0 : hbuf1;

    // ---- A: hWh[b][sub*64 .. +64) = h[b] @ Wh^T + attn_b ----
    scr[tid] = h_in[b*512 + tid];
    __syncthreads();
    {
      const int jl = tid >> 3, ks = tid & 7;
      const int jc = sub*64 + jl;
      const float* wr = attn_W + (size_t)jc*1024 + 512 + ks*64;
      const float* xr = scr + ks*64;
      float a = 0.f;
      #pragma unroll
      for (int i = 0; i < 64; i += 8){
        float4 w0 = *(const float4*)(wr + i), w1 = *(const float4*)(wr + i + 4);
        float4 x0 = *(const float4*)(xr + i), x1 = *(const float4*)(xr + i + 4);
        a += dot4(w0, x0) + dot4(w1, x1);
      }
      a += __shfl_xor(a, 1); a += __shfl_xor(a, 2); a += __shfl_xor(a, 4);
      if (ks == 0) hWh_g[b*512 + jc] = a + attn_b[jc];
    }
    bar_arrive_wait(mcnt, mgen, 8, ++mi);

    // ---- B: scores for p ≡ sub (mod 8) ----
    {
      const int l = tid & 63, w = tid >> 6;
      float4 hv0 = *(const float4*)(hWh_g + b*512 + l*8);
      float4 hv1 = *(const float4*)(hWh_g + b*512 + l*8 + 4);
      float4 vv0 = *(const float4*)(vws + l*8);
      float4 vv1 = *(const float4*)(vws + l*8 + 4);
      for (int p = sub + 8*w; p < P; p += 64){
        const float* fp = feat_proj + ((size_t)b*P + p)*512 + l*8;
        float4 f0 = *(const float4*)fp;
        float4 f1 = *(const float4*)(fp + 4);
        float a = vv0.x*fast_tanh(f0.x + hv0.x);
        a += vv0.y*fast_tanh(f0.y + hv0.y);
        a += vv0.z*fast_tanh(f0.z + hv0.z);
        a += vv0.w*fast_tanh(f0.w + hv0.w);
        a += vv1.x*fast_tanh(f1.x + hv1.x);
        a += vv1.y*fast_tanh(f1.y + hv1.y);
        a += vv1.z*fast_tanh(f1.z + hv1.z);
        a += vv1.w*fast_tanh(f1.w + hv1.w);
        #pragma unroll
        for (int off = 32; off; off >>= 1) a += __shfl_xor(a, off);
        if (l == 0) sc_g[b*256 + p] = a;
      }
    }
    bar_arrive_wait(mcnt, mgen, 8, ++mi);

    // ---- C: softmax (redundant x8) + ctx slice e in [sub*64, +64) ----
    {
      float* alpha = scr;           // [200]
      float* invp  = scr + 200;
      float* partc = scr + 208;     // [8][68]
      if (tid < 64){
        const float* sb = sc_g + b*256;
        float v0 = sb[tid], v1 = sb[tid + 64], v2 = sb[tid + 128];
        float v3 = (tid < 4) ? sb[tid + 192] : -1e30f;
        float m = fmaxf(fmaxf(v0, v1), fmaxf(v2, v3));
        #pragma unroll
        for (int off = 32; off; off >>= 1) m = fmaxf(m, __shfl_xor(m, off));
        float e0 = __expf(v0 - m), e1 = __expf(v1 - m), e2 = __expf(v2 - m);
        float e3 = (tid < 4) ? __expf(v3 - m) : 0.f;
        alpha[tid] = e0; alpha[tid + 64] = e1; alpha[tid + 128] = e2;
        if (tid < 4) alpha[tid + 192] = e3;
        float s = e0 + e1 + e2 + e3;
        #pragma unroll
        for (int off = 32; off; off >>= 1) s += __shfl_xor(s, off);
        if (tid == 0) invp[0] = 1.0f/s;
      }
      __syncthreads();
      {
        const int e = sub*64 + (tid & 63), ps = tid >> 6;
        float a = 0.f;
        for (int p = ps; p < P; p += 8)
          a += alpha[p] * feats[((size_t)b*P + p)*512 + e];
        partc[ps*68 + (tid & 63)] = a;
      }
      __syncthreads();
      if (tid < 64){
        float s = 0.f;
        #pragma unroll
        for (int k = 0; k < 8; ++k) s += partc[k*68 + tid];
        ctx_g[b*512 + sub*64 + tid] = s * invp[0];
      }
    }
    bar_arrive_wait(gcnt, ggen, NB, ++gi);

    // ---- D: gates for j in {jb, jb+1} x 4 gates, all 32 batches ----
    {
      const int kh = tid >> 8, o = tid & 255, bb = o >> 3, c = o & 7;
      const float* wrow = &Wl[c][kh*768];
      float a = 0.f;
      if (kh == 0){
        const float4* xe = (const float4*)(emb + ((size_t)bb*T + t)*512);
        const float4* wv = (const float4*)wrow;
        #pragma unroll 8
        for (int i = 0; i < 128; ++i) a += dot4(wv[i], xe[i]);
        const float4* xc = (const float4*)(ctx_g + bb*512);
        const float4* wv2 = (const float4*)(wrow + 512);
        #pragma unroll 8
        for (int i = 0; i < 64; ++i) a += dot4(wv2[i], xc[i]);
      } else {
        const float4* xc = (const float4*)(ctx_g + bb*512 + 256);
        const float4* wv = (const float4*)wrow;
        #pragma unroll 8
        for (int i = 0; i < 64; ++i) a += dot4(wv[i], xc[i]);
        const float4* xh = (const float4*)(h_in + bb*512);
        const float4* wv2 = (const float4*)(wrow + 256);
        #pragma unroll 8
        for (int i = 0; i < 128; ++i) a += dot4(wv2[i], xh[i]);
      }
      scr[kh*256 + o] = a;
    }
    __syncthreads();
    if (tid < 256) scr[512 + tid] = scr[tid] + scr[256 + tid];
    __syncthreads();
    if (tid < 64){
      const int bb = tid >> 1, jj = tid & 1;
      float gv[4];
      #pragma unroll
      for (int g = 0; g < 4; ++g)
        gv[g] = scr[512 + bb*8 + g*2 + jj] + bias8[g*2 + jj];
      const float i_ = sigmoidf_(gv[0]);
      const float f_ = sigmoidf_(gv[1]);
      const float g_ = fast_tanh(gv[2]);
      const float o_ = sigmoidf_(gv[3]);
      const int j = jb + jj;
      const float c_old = c_state[bb*512 + j];
      const float c_new = f_*c_old + i_*g_;
      const float h_new = o_*fast_tanh(c_new);
      c_state[bb*512 + j] = c_new;
      h_out[bb*512 + j] = h_new;
      const unsigned short hh = f_to_bf16(h_new);
      hall_h[((size_t)bb*T + t)*512 + j] = hh;
      hall_l[((size_t)bb*T + t)*512 + j] = f_to_bf16(h_new - bf16_to_f(hh));
    }
    bar_arrive_wait(gcnt, ggen, NB, ++gi);
  }
}

// ---------------------------------------------------------------------------
extern "C" void kernel_launch(void* const* d_in, const int* in_sizes, int n_in,
                              void* d_out, int out_size, void* d_ws, size_t ws_size,
                              hipStream_t stream)
{
  (void)in_sizes; (void)n_in; (void)out_size;
  const float* features = (const float*)d_in[0];
  const int*   captions = (const int*)d_in[1];
  const float* embed_W  = (const float*)d_in[2];
  const float* attn_W   = (const float*)d_in[3];
  const float* attn_b   = (const float*)d_in[4];
  const float* v_w      = (const float*)d_in[5];
  const float* W_ih     = (const float*)d_in[6];
  const float* W_hh     = (const float*)d_in[7];
  const float* b_ih     = (const float*)d_in[8];
  const float* b_hh     = (const float*)d_in[9];
  const float* lin_W    = (const float*)d_in[10];
  const float* lin_b    = (const float*)d_in[11];
  const float* inith_W  = (const float*)d_in[12];
  const float* inith_b  = (const float*)d_in[13];
  const float* initc_W  = (const float*)d_in[14];
  const float* initc_b  = (const float*)d_in[15];

  // "early" scratch in d_out (dead before final logits GEMM writes d_out)
  char* o = (char*)d_out;
  unsigned short* feat_bf   = (unsigned short*)o; o += (size_t)(B*P)*E*2;   // 6.4MB
  unsigned short* Wf_bf     = (unsigned short*)o; o += (size_t)H*E*2;       // 0.5MB
  float*          feat_proj = (float*)o;          o += (size_t)(B*P)*H*4;   // 12.9MB

  // persistent scratch in d_ws
  const size_t SZ_LIN  = (size_t)V*H*2;          // 32.77MB
  const size_t SZ_HALL = (size_t)(B*T)*H*2;      // 1MB
  const size_t SZ_EMB  = (size_t)(B*T)*E*4;      // 2.1MB
  const size_t SZ_ST   = (size_t)B*H*4;          // 64KB
  const size_t SZ_SC   = (size_t)B*256*4;        // 32KB
  const size_t SZ_BAR  = 16384;
  const size_t base_need = SZ_LIN + 2*SZ_HALL + SZ_EMB + 6*SZ_ST + SZ_SC + SZ_BAR;
  const bool three = (ws_size >= base_need + SZ_LIN);

  char* w = (char*)d_ws;
  unsigned short* lin_hi  = (unsigned short*)w; w += SZ_LIN;
  unsigned short* lin_lo  = (unsigned short*)w; if (three) w += SZ_LIN;
  unsigned short* hall_hi = (unsigned short*)w; w += SZ_HALL;
  unsigned short* hall_lo = (unsigned short*)w; w += SZ_HALL;
  float*          emb_ws  = (float*)w;          w += SZ_EMB;
  float*          hbuf0   = (float*)w;          w += SZ_ST;
  float*          hbuf1   = (float*)w;          w += SZ_ST;
  float*          c_state = (float*)w;          w += SZ_ST;
  float*          hWh_ws  = (float*)w;          w += SZ_ST;
  float*          ctx_ws  = (float*)w;          w += SZ_ST;
  float*          sc_ws   = (float*)w;          w += SZ_SC;
  unsigned*       bars    = (unsigned*)w;       w += SZ_BAR;

  // --- conversions / gathers / init ---
  split_kernel<<<2048, 256, 0, stream>>>(features, E, 0, B*P, feat_bf, nullptr, E, 0);
  split_kernel<<<256, 256, 0, stream>>>(attn_W, E+H, 0, H, Wf_bf, nullptr, E, 0);
  split_kernel<<<2048, 256, 0, stream>>>(lin_W, 512, 0, V, lin_hi, three ? lin_lo : nullptr, 512, 0);
  embed_kernel<<<B*T, 128, 0, stream>>>(captions, embed_W, emb_ws);
  prep_kernel<<<B, 512, 0, stream>>>(features, inith_W, inith_b, initc_W, initc_b,
                                     hbuf0, c_state);
  hipMemsetAsync(bars, 0, SZ_BAR, stream);

  // feat_proj = features @ Wf^T (bf16 1-pass; error damped through tanh/softmax)
  gemm_bt_kernel<<<(B*P/128)*(E/128), 256, 0, stream>>>(
      feat_bf, feat_bf, feat_bf, Wf_bf, Wf_bf, Wf_bf,
      feat_proj, nullptr, E, E, 1, B*P/128, 0);

  // --- the whole recurrence in one persistent kernel ---
  loop_kernel<<<NB, NT, 0, stream>>>(
      features, feat_proj, attn_W, attn_b, v_w, emb_ws, W_ih, W_hh, b_ih, b_hh,
      hbuf0, hbuf1, c_state, hWh_ws, sc_ws, ctx_ws, hall_hi, hall_lo, bars);

  // --- logits = h_all @ lin_W^T + lin_b (bf16x3, XCD-swizzled grid) ---
  gemm_bt_kernel<<<(V/128)*(B*T/128), 256, 0, stream>>>(
      hall_hi, hall_lo, hall_hi, lin_hi, lin_hi, three ? lin_lo : lin_hi,
      (float*)d_out, lin_b, V, H, three ? 3 : 2, B*T/128, 1);
}

// Round 6
// 2212.109 us; speedup vs baseline: 1.6783x; 1.6783x over previous
//
// CaptionDecoder on MI355X — round 5 (re-ship of r3/r4 design, fence fix):
// persistent loop with flag-array barriers (no contended RMW), A+B fusion,
// transposed Wh for coalesced conflict-free phase A, c_state in registers.
#include <hip/hip_runtime.h>

#define E 512
#define H 512
#define V 32000
#define B 32
#define P 196
#define T 32
#define NB 256
#define NT 512

typedef __attribute__((ext_vector_type(8))) short s8v;    // 8 bf16
typedef __attribute__((ext_vector_type(4))) float f4v;    // 4 f32 acc

__device__ __forceinline__ float bf16_to_f(unsigned short u){
  return __uint_as_float(((unsigned)u) << 16);
}
__device__ __forceinline__ unsigned short f_to_bf16(float f){
  unsigned u = __float_as_uint(f);
  u += 0x7FFFu + ((u >> 16) & 1u);   // RNE
  return (unsigned short)(u >> 16);
}
__device__ __forceinline__ float fast_tanh(float x){
  float e = __expf(2.0f*x);
  return 1.0f - 2.0f/(e + 1.0f);
}
__device__ __forceinline__ float sigmoidf_(float x){
  return 1.0f/(1.0f + __expf(-x));
}
__device__ __forceinline__ void load_lds16(const unsigned short* g, unsigned short* l){
  __builtin_amdgcn_global_load_lds(
      (const __attribute__((address_space(1))) void*)g,
      (__attribute__((address_space(3))) void*)l, 16, 0, 0);
}
__device__ __forceinline__ float dot4(float4 a, float4 b){
  return a.x*b.x + a.y*b.y + a.z*b.z + a.w*b.w;
}

#define AT_SCOPE __HIP_MEMORY_SCOPE_AGENT
// Flag-array barrier: block publishes its own word (release), wave 0 polls all
// n flags relaxed until min >= gen, then acquire fence. No contended RMW.
__device__ __forceinline__ void bar_flag(unsigned* my, const unsigned* wait_base,
                                         int n, unsigned gen){
  __syncthreads();                      // all waves' prior stores issued
  if (threadIdx.x == 0)
    __hip_atomic_store(my, gen, __ATOMIC_RELEASE, AT_SCOPE);
  if (threadIdx.x < 64){
    for (;;){
      unsigned mn = 0xffffffffu;
      for (int i = (int)threadIdx.x; i < n; i += 64){
        unsigned v = __hip_atomic_load(wait_base + i, __ATOMIC_RELAXED, AT_SCOPE);
        mn = v < mn ? v : mn;
      }
      #pragma unroll
      for (int off = 32; off; off >>= 1){
        unsigned o2 = (unsigned)__shfl_xor((int)mn, off);
        mn = o2 < mn ? o2 : mn;
      }
      if (mn >= gen) break;
      __builtin_amdgcn_s_sleep(2);
    }
    __builtin_amdgcn_fence(__ATOMIC_ACQUIRE, "agent");
  }
  __syncthreads();
}

// ---------------------------------------------------------------------------
// f32 (strided) -> bf16 hi (+ optional lo residual). cols==512.
__global__ void split_kernel(const float* __restrict__ src, int src_ld, int src_coff,
                             int rows,
                             unsigned short* __restrict__ dhi, unsigned short* __restrict__ dlo,
                             int dst_ld, int dst_coff)
{
  int n = rows << 9;
  for (int i = blockIdx.x*blockDim.x + threadIdx.x; i < n; i += gridDim.x*blockDim.x){
    int r = i >> 9, c = i & 511;
    float x = src[(size_t)r*src_ld + src_coff + c];
    unsigned short h = f_to_bf16(x);
    dhi[(size_t)r*dst_ld + dst_coff + c] = h;
    if (dlo) dlo[(size_t)r*dst_ld + dst_coff + c] = f_to_bf16(x - bf16_to_f(h));
  }
}

// Embedding gather -> f32, row = b*T+t
__global__ void embed_kernel(const int* __restrict__ caps, const float* __restrict__ embW,
                             float* __restrict__ emb)
{
  int row = blockIdx.x;
  int cap = caps[row];
  const float4* s = (const float4*)(embW + (size_t)cap*E);
  float4* d = (float4*)(emb + (size_t)row*E);
  for (int e = threadIdx.x; e < E/4; e += blockDim.x) d[e] = s[e];
}

// mean over P, then h0/c0 = mean@W^T + b
__global__ __launch_bounds__(512) void prep_kernel(
    const float* __restrict__ feats,
    const float* __restrict__ inith_W, const float* __restrict__ inith_b,
    const float* __restrict__ initc_W, const float* __restrict__ initc_b,
    float* __restrict__ h_state, float* __restrict__ c_state)
{
  __shared__ float mf[E];
  const int b = blockIdx.x, tid = threadIdx.x;
  const float* fb = feats + (size_t)b*P*E + tid;
  float s = 0.f;
  for (int p = 0; p < P; ++p) s += fb[(size_t)p*E];
  mf[tid] = s * (1.0f/196.0f);
  __syncthreads();
  const float* wh = inith_W + (size_t)tid*E;
  const float* wc = initc_W + (size_t)tid*E;
  float h0 = inith_b[tid], c0 = initc_b[tid];
  #pragma unroll 4
  for (int e = 0; e < E; e += 4){
    float4 a4 = *(const float4*)(wh + e);
    float4 b4 = *(const float4*)(wc + e);
    float4 m4 = *(const float4*)(mf + e);
    h0 += dot4(a4, m4);
    c0 += dot4(b4, m4);
  }
  h_state[b*H + tid] = h0;
  c_state[b*H + tid] = c0;
}

// WhT[k][j] = attn_W[j][E + k]  (64x64 LDS tiles, coalesced both sides)
__global__ __launch_bounds__(256) void transpose_wh_kernel(
    const float* __restrict__ attn_W, float* __restrict__ WhT)
{
  __shared__ float tile[64][65];
  const int jt = blockIdx.x & 7, kt = blockIdx.x >> 3;
  const int tx = threadIdx.x & 63, ty = threadIdx.x >> 6;
  for (int r = ty; r < 64; r += 4)
    tile[r][tx] = attn_W[(size_t)(jt*64 + r)*(E+H) + E + kt*64 + tx];
  __syncthreads();
  for (int r = ty; r < 64; r += 4)
    WhT[(size_t)(kt*64 + r)*512 + jt*64 + tx] = tile[tx][r];
}

// ---------------------------------------------------------------------------
// m97-style bf16 GEMM: C = sum_passes A_p (MxK) * B_p(NxK)^T [+bias]
__global__ __launch_bounds__(256) void gemm_bt_kernel(
    const unsigned short* __restrict__ A0, const unsigned short* __restrict__ A1,
    const unsigned short* __restrict__ A2,
    const unsigned short* __restrict__ B0, const unsigned short* __restrict__ B1,
    const unsigned short* __restrict__ B2,
    float* __restrict__ Cc, const float* __restrict__ bias,
    int N, int K, int npasses, int mt, int swz)
{
  __shared__ __align__(16) unsigned short Al[128*32];
  __shared__ __align__(16) unsigned short Bl[128*32];
  const int tid = threadIdx.x;
  const int wid = tid >> 6, l = tid & 63;
  int f = blockIdx.x;
  if (swz) f = (f & 7)*((int)gridDim.x >> 3) + (f >> 3);
  const int m0 = (f % mt)*128, n0 = (f / mt)*128;
  const int wr = wid >> 1, wc = wid & 1;

  f4v acc[4][4];
  #pragma unroll
  for (int i = 0; i < 4; ++i)
    #pragma unroll
    for (int j = 0; j < 4; ++j) acc[i][j] = (f4v){0.f,0.f,0.f,0.f};

  const int s0 = tid, s1 = tid + 256;
  const int r0 = s0 >> 2, g0 = (s0 & 3) ^ ((r0 >> 1) & 3);
  const int r1 = s1 >> 2, g1 = (s1 & 3) ^ ((r1 >> 1) & 3);
  const int la = l & 15, ch = l >> 4;

  for (int pass = 0; pass < npasses; ++pass){
    const unsigned short* Ap = pass == 0 ? A0 : (pass == 1 ? A1 : A2);
    const unsigned short* Bp = pass == 0 ? B0 : (pass == 1 ? B1 : B2);
    for (int k0 = 0; k0 < K; k0 += 32){
      __syncthreads();
      load_lds16(Ap + (size_t)(m0 + r0)*K + k0 + g0*8, Al + s0*8);
      load_lds16(Ap + (size_t)(m0 + r1)*K + k0 + g1*8, Al + s1*8);
      load_lds16(Bp + (size_t)(n0 + r0)*K + k0 + g0*8, Bl + s0*8);
      load_lds16(Bp + (size_t)(n0 + r1)*K + k0 + g1*8, Bl + s1*8);
      __syncthreads();
      s8v av[4], bv[4];
      #pragma unroll
      for (int mi = 0; mi < 4; ++mi){
        int row = wr*64 + mi*16 + la;
        int cs = ch ^ ((row >> 1) & 3);
        av[mi] = *(const s8v*)(Al + (row*4 + cs)*8);
      }
      #pragma unroll
      for (int ni = 0; ni < 4; ++ni){
        int row = wc*64 + ni*16 + la;
        int cs = ch ^ ((row >> 1) & 3);
        bv[ni] = *(const s8v*)(Bl + (row*4 + cs)*8);
      }
      #pragma unroll
      for (int mi = 0; mi < 4; ++mi)
        #pragma unroll
        for (int ni = 0; ni < 4; ++ni)
          acc[mi][ni] = __builtin_amdgcn_mfma_f32_16x16x32_bf16(av[mi], bv[ni], acc[mi][ni], 0, 0, 0);
    }
  }
  #pragma unroll
  for (int mi = 0; mi < 4; ++mi){
    int row = m0 + wr*64 + mi*16 + (l >> 4)*4;
    #pragma unroll
    for (int ni = 0; ni < 4; ++ni){
      int col = n0 + wc*64 + ni*16 + (l & 15);
      float bb = bias ? bias[col] : 0.0f;
      #pragma unroll
      for (int r = 0; r < 4; ++r)
        Cc[(size_t)(row + r)*N + col] = acc[mi][ni][r] + bb;
    }
  }
}

// ---------------------------------------------------------------------------
// Persistent loop kernel. blk -> (b = blk&31, sub = blk>>5) for attention
// phases; blk owns j-pair {2blk, 2blk+1} x 4 gates for LSTM (weights in LDS).
// Per step: [A+B fused] -mini(8)- [C] -grid- [D] -grid-.
__global__ __launch_bounds__(512, 1) void loop_kernel(
    const float* __restrict__ feats, const float* __restrict__ feat_proj,
    const float* __restrict__ WhT, const float* __restrict__ attn_b,
    const float* __restrict__ v_w, const float* __restrict__ emb,
    const float* __restrict__ W_ih, const float* __restrict__ W_hh,
    const float* __restrict__ b_ih, const float* __restrict__ b_hh,
    float* __restrict__ hbuf0, float* __restrict__ hbuf1,
    const float* __restrict__ c_init,
    float* __restrict__ ctx_g, float* __restrict__ s_part,
    unsigned short* __restrict__ hall_h, unsigned short* __restrict__ hall_l,
    unsigned* __restrict__ fm, unsigned* __restrict__ fg1, unsigned* __restrict__ fg2)
{
  __shared__ float Wl[8][1540];   // 49.3KB gate-weight rows [Wih(1024)|Whh(512)]
  __shared__ float hs[512];
  __shared__ float hwl[64];
  __shared__ float partA[8][72];
  __shared__ float scr[1024];
  __shared__ float aux[256];
  __shared__ float bias8[8];
  __shared__ float smx, sinv;

  const int blk = blockIdx.x, tid = threadIdx.x;
  const int b = blk & 31, sub = blk >> 5;
  const int jb = blk*2;
  const int l = tid & 63, wv = tid >> 6;

  // ---- prologue: park gate weights in LDS, init registers ----
  #pragma unroll
  for (int r = 0; r < 8; ++r){
    const int col = (r >> 1)*512 + jb + (r & 1);
    const float4* wi = (const float4*)(W_ih + (size_t)col*1024);
    const float4* wh = (const float4*)(W_hh + (size_t)col*512);
    float4* d0 = (float4*)&Wl[r][0];
    float4* d1 = (float4*)&Wl[r][1024];
    for (int q = tid; q < 256; q += NT) d0[q] = wi[q];
    for (int q = tid; q < 128; q += NT) d1[q] = wh[q];
  }
  if (tid < 8){
    const int col = (tid >> 1)*512 + jb + (tid & 1);
    bias8[tid] = b_ih[col] + b_hh[col];
  }
  const float vl = v_w[sub*64 + l];
  const float ab = (tid < 64) ? attn_b[sub*64 + tid] : 0.f;
  float c_reg = 0.f;
  if (tid < 64) c_reg = c_init[(tid >> 1)*512 + jb + (tid & 1)];
  __syncthreads();

  for (int t = 0; t < T; ++t){
    const float* h_in  = (t & 1) ? hbuf1 : hbuf0;
    float*       h_out = (t & 1) ? hbuf0 : hbuf1;
    const unsigned gen = (unsigned)(t + 1);

    // ---- A: hWh[b][sub*64..+64) into LDS (coalesced WhT, broadcast h) ----
    hs[tid] = h_in[b*512 + tid];
    __syncthreads();
    {
      const float* wt = WhT + (size_t)(wv*64)*512 + sub*64 + l;
      const float* hk = hs + wv*64;
      float a = 0.f;
      #pragma unroll 8
      for (int kk = 0; kk < 64; ++kk) a += hk[kk] * wt[(size_t)kk*512];
      partA[wv][l] = a;
    }
    __syncthreads();
    if (tid < 64){
      float s = ab;
      #pragma unroll
      for (int k = 0; k < 8; ++k) s += partA[k][tid];
      hwl[tid] = s;
    }
    __syncthreads();

    // ---- B: partial scores over own j-slice (hWh never leaves LDS) ----
    {
      const float hj = hwl[l];
      for (int p = wv; p < P; p += 8){
        float fp = feat_proj[((size_t)b*P + p)*512 + sub*64 + l];
        float e2 = vl * fast_tanh(fp + hj);
        #pragma unroll
        for (int off = 32; off; off >>= 1) e2 += __shfl_xor(e2, off);
        if (l == 0) s_part[((size_t)b*P + p)*8 + sub] = e2;
      }
    }
    bar_flag(fm + b*8 + sub, fm + b*8, 8, gen);

    // ---- C: reduce partials -> softmax -> ctx slice ----
    {
      float sc_v = -1e30f;
      if (tid < P){
        const float* sp = s_part + ((size_t)b*P + tid)*8;
        float4 q0 = *(const float4*)sp, q1 = *(const float4*)(sp + 4);
        sc_v = (q0.x + q0.y + q0.z + q0.w) + (q1.x + q1.y + q1.z + q1.w);
      }
      if (tid < 256) aux[tid] = sc_v;
      __syncthreads();
      if (tid < 64){
        float m = -1e30f;
        #pragma unroll
        for (int i = 0; i < 4; ++i) m = fmaxf(m, aux[tid + i*64]);
        #pragma unroll
        for (int off = 32; off; off >>= 1) m = fmaxf(m, __shfl_xor(m, off));
        if (tid == 0) smx = m;
      }
      __syncthreads();
      float al = (tid < P) ? __expf(sc_v - smx) : 0.f;
      if (tid < 256) aux[tid] = al;
      __syncthreads();
      if (tid < 64){
        float s = 0.f;
        #pragma unroll
        for (int i = 0; i < 4; ++i) s += aux[tid + i*64];
        #pragma unroll
        for (int off = 32; off; off >>= 1) s += __shfl_xor(s, off);
        if (tid == 0) sinv = 1.0f/s;
      }
      __syncthreads();
      float a = 0.f;
      for (int p = wv; p < P; p += 8)
        a += aux[p] * feats[((size_t)b*P + p)*512 + sub*64 + l];
      partA[wv][l] = a;
      __syncthreads();
      if (tid < 64){
        float s = 0.f;
        #pragma unroll
        for (int k = 0; k < 8; ++k) s += partA[k][tid];
        ctx_g[b*512 + sub*64 + tid] = s * sinv;
      }
    }
    bar_flag(fg1 + blk, fg1, NB, gen);

    // ---- D: gates for j in {jb, jb+1} x 4 gates, all 32 batches ----
    {
      const int kh = tid >> 8, o = tid & 255, bb = o >> 3, c = o & 7;
      const float* wrow = &Wl[c][kh*768];
      float a = 0.f;
      if (kh == 0){
        const float4* xe = (const float4*)(emb + ((size_t)bb*T + t)*512);
        const float4* wvp = (const float4*)wrow;
        #pragma unroll 8
        for (int i = 0; i < 128; ++i) a += dot4(wvp[i], xe[i]);
        const float4* xc = (const float4*)(ctx_g + bb*512);
        const float4* wv2 = (const float4*)(wrow + 512);
        #pragma unroll 8
        for (int i = 0; i < 64; ++i) a += dot4(wv2[i], xc[i]);
      } else {
        const float4* xc = (const float4*)(ctx_g + bb*512 + 256);
        const float4* wvp = (const float4*)wrow;
        #pragma unroll 8
        for (int i = 0; i < 64; ++i) a += dot4(wvp[i], xc[i]);
        const float4* xh = (const float4*)(h_in + bb*512);
        const float4* wv2 = (const float4*)(wrow + 256);
        #pragma unroll 8
        for (int i = 0; i < 128; ++i) a += dot4(wv2[i], xh[i]);
      }
      scr[kh*256 + o] = a;
    }
    __syncthreads();
    if (tid < 256) scr[512 + tid] = scr[tid] + scr[256 + tid];
    __syncthreads();
    if (tid < 64){
      const int bb = tid >> 1, jj = tid & 1;
      float gv[4];
      #pragma unroll
      for (int g = 0; g < 4; ++g)
        gv[g] = scr[512 + bb*8 + g*2 + jj] + bias8[g*2 + jj];
      const float i_ = sigmoidf_(gv[0]);
      const float f_ = sigmoidf_(gv[1]);
      const float g_ = fast_tanh(gv[2]);
      const float o_ = sigmoidf_(gv[3]);
      const int j = jb + jj;
      const float c_new = f_*c_reg + i_*g_;
      const float h_new = o_*fast_tanh(c_new);
      c_reg = c_new;
      h_out[bb*512 + j] = h_new;
      const unsigned short hh = f_to_bf16(h_new);
      hall_h[((size_t)bb*T + t)*512 + j] = hh;
      hall_l[((size_t)bb*T + t)*512 + j] = f_to_bf16(h_new - bf16_to_f(hh));
    }
    bar_flag(fg2 + blk, fg2, NB, gen);
  }
}

// ---------------------------------------------------------------------------
extern "C" void kernel_launch(void* const* d_in, const int* in_sizes, int n_in,
                              void* d_out, int out_size, void* d_ws, size_t ws_size,
                              hipStream_t stream)
{
  (void)in_sizes; (void)n_in; (void)out_size;
  const float* features = (const float*)d_in[0];
  const int*   captions = (const int*)d_in[1];
  const float* embed_W  = (const float*)d_in[2];
  const float* attn_W   = (const float*)d_in[3];
  const float* attn_b   = (const float*)d_in[4];
  const float* v_w      = (const float*)d_in[5];
  const float* W_ih     = (const float*)d_in[6];
  const float* W_hh     = (const float*)d_in[7];
  const float* b_ih     = (const float*)d_in[8];
  const float* b_hh     = (const float*)d_in[9];
  const float* lin_W    = (const float*)d_in[10];
  const float* lin_b    = (const float*)d_in[11];
  const float* inith_W  = (const float*)d_in[12];
  const float* inith_b  = (const float*)d_in[13];
  const float* initc_W  = (const float*)d_in[14];
  const float* initc_b  = (const float*)d_in[15];

  // "early" scratch in d_out (dead before final logits GEMM writes d_out)
  char* o = (char*)d_out;
  unsigned short* feat_bf   = (unsigned short*)o; o += (size_t)(B*P)*E*2;   // 6.4MB
  unsigned short* Wf_bf     = (unsigned short*)o; o += (size_t)H*E*2;       // 0.5MB
  float*          feat_proj = (float*)o;          o += (size_t)(B*P)*H*4;   // 12.9MB

  // persistent scratch in d_ws
  const size_t SZ_LIN  = (size_t)V*H*2;          // 32.77MB
  const size_t SZ_HALL = (size_t)(B*T)*H*2;      // 1MB
  const size_t SZ_EMB  = (size_t)(B*T)*E*4;      // 2.1MB
  const size_t SZ_ST   = (size_t)B*H*4;          // 64KB
  const size_t SZ_WHT  = (size_t)H*H*4;          // 1MB
  const size_t SZ_SP   = (size_t)B*P*8*4;        // 0.2MB
  const size_t SZ_FLG  = 4096;
  const size_t need_wo = SZ_LIN + 2*SZ_HALL + SZ_EMB + 5*SZ_ST + SZ_WHT + SZ_SP + SZ_FLG;
  const bool three = (ws_size >= need_wo + SZ_LIN);

  char* w = (char*)d_ws;
  unsigned short* lin_hi  = (unsigned short*)w; w += SZ_LIN;
  unsigned short* lin_lo  = (unsigned short*)w; if (three) w += SZ_LIN;
  unsigned short* hall_hi = (unsigned short*)w; w += SZ_HALL;
  unsigned short* hall_lo = (unsigned short*)w; w += SZ_HALL;
  float*          emb_ws  = (float*)w;          w += SZ_EMB;
  float*          hbuf0   = (float*)w;          w += SZ_ST;
  float*          hbuf1   = (float*)w;          w += SZ_ST;
  float*          c_state = (float*)w;          w += SZ_ST;
  float*          ctx_ws  = (float*)w;          w += SZ_ST;
  float*          WhT_ws  = (float*)w;          w += SZ_WHT;
  float*          spart   = (float*)w;          w += SZ_SP;
  unsigned*       flags   = (unsigned*)w;       w += SZ_FLG;
  unsigned* fm  = flags;          // [256] mini-barrier flags [b*8+sub]
  unsigned* fg1 = flags + 256;    // [256] grid barrier 1
  unsigned* fg2 = flags + 512;    // [256] grid barrier 2

  // --- conversions / gathers / init ---
  split_kernel<<<2048, 256, 0, stream>>>(features, E, 0, B*P, feat_bf, nullptr, E, 0);
  split_kernel<<<256, 256, 0, stream>>>(attn_W, E+H, 0, H, Wf_bf, nullptr, E, 0);
  split_kernel<<<2048, 256, 0, stream>>>(lin_W, 512, 0, V, lin_hi, three ? lin_lo : nullptr, 512, 0);
  embed_kernel<<<B*T, 128, 0, stream>>>(captions, embed_W, emb_ws);
  prep_kernel<<<B, 512, 0, stream>>>(features, inith_W, inith_b, initc_W, initc_b,
                                     hbuf0, c_state);
  transpose_wh_kernel<<<64, 256, 0, stream>>>(attn_W, WhT_ws);
  hipMemsetAsync(flags, 0, SZ_FLG, stream);

  // feat_proj = features @ Wf^T (bf16 1-pass; error damped through tanh/softmax)
  gemm_bt_kernel<<<(B*P/128)*(E/128), 256, 0, stream>>>(
      feat_bf, feat_bf, feat_bf, Wf_bf, Wf_bf, Wf_bf,
      feat_proj, nullptr, E, E, 1, B*P/128, 0);

  // --- the whole recurrence in one persistent kernel ---
  loop_kernel<<<NB, NT, 0, stream>>>(
      features, feat_proj, WhT_ws, attn_b, v_w, emb_ws, W_ih, W_hh, b_ih, b_hh,
      hbuf0, hbuf1, c_state, ctx_ws, spart, hall_hi, hall_lo, fm, fg1, fg2);

  // --- logits = h_all @ lin_W^T + lin_b (bf16x3, XCD-swizzled grid) ---
  gemm_bt_kernel<<<(V/128)*(B*T/128), 256, 0, stream>>>(
      hall_hi, hall_lo, hall_hi, lin_hi, lin_hi, three ? lin_lo : lin_hi,
      (float*)d_out, lin_b, V, H, three ? 3 : 2, B*T/128, 1);
}

// Round 7
// 2103.265 us; speedup vs baseline: 1.7651x; 1.0518x over previous
//
// CaptionDecoder on MI355X — round 7: LDS-park step-invariant attention data.
// R6 counters: loop FETCH=373MB @204GB/s = per-step refetch of feat_proj/feats
// (agent acquire fences defeat L2 retention). Fix: park per-block feat_proj
// slice (f32) + features slice (bf16) in LDS for all 32 steps.
#include <hip/hip_runtime.h>

#define E 512
#define H 512
#define V 32000
#define B 32
#define P 196
#define T 32
#define NB 256
#define NT 512

typedef __attribute__((ext_vector_type(8))) short s8v;    // 8 bf16
typedef __attribute__((ext_vector_type(4))) float f4v;    // 4 f32 acc

__device__ __forceinline__ float bf16_to_f(unsigned short u){
  return __uint_as_float(((unsigned)u) << 16);
}
__device__ __forceinline__ unsigned short f_to_bf16(float f){
  unsigned u = __float_as_uint(f);
  u += 0x7FFFu + ((u >> 16) & 1u);   // RNE
  return (unsigned short)(u >> 16);
}
__device__ __forceinline__ float fast_tanh(float x){
  float e = __expf(2.0f*x);
  return 1.0f - 2.0f/(e + 1.0f);
}
__device__ __forceinline__ float sigmoidf_(float x){
  return 1.0f/(1.0f + __expf(-x));
}
__device__ __forceinline__ void load_lds16(const unsigned short* g, unsigned short* l){
  __builtin_amdgcn_global_load_lds(
      (const __attribute__((address_space(1))) void*)g,
      (__attribute__((address_space(3))) void*)l, 16, 0, 0);
}
__device__ __forceinline__ float dot4(float4 a, float4 b){
  return a.x*b.x + a.y*b.y + a.z*b.z + a.w*b.w;
}

#define AT_SCOPE __HIP_MEMORY_SCOPE_AGENT
// Flag-array barrier: block publishes its own word (release), wave 0 polls all
// n flags relaxed until min >= gen, then acquire fence. No contended RMW.
__device__ __forceinline__ void bar_flag(unsigned* my, const unsigned* wait_base,
                                         int n, unsigned gen){
  __syncthreads();                      // all waves' prior stores issued
  if (threadIdx.x == 0){
    __builtin_amdgcn_fence(__ATOMIC_RELEASE, "agent");   // drain block's stores
    __hip_atomic_store(my, gen, __ATOMIC_RELEASE, AT_SCOPE);
  }
  if (threadIdx.x < 64){
    for (;;){
      unsigned mn = 0xffffffffu;
      for (int i = (int)threadIdx.x; i < n; i += 64){
        unsigned v = __hip_atomic_load(wait_base + i, __ATOMIC_RELAXED, AT_SCOPE);
        mn = v < mn ? v : mn;
      }
      #pragma unroll
      for (int off = 32; off; off >>= 1){
        unsigned o2 = (unsigned)__shfl_xor((int)mn, off);
        mn = o2 < mn ? o2 : mn;
      }
      if (mn >= gen) break;
      __builtin_amdgcn_s_sleep(1);
    }
    __builtin_amdgcn_fence(__ATOMIC_ACQUIRE, "agent");
  }
  __syncthreads();
}

// ---------------------------------------------------------------------------
// f32 (strided) -> bf16 hi (+ optional lo residual). cols==512.
__global__ void split_kernel(const float* __restrict__ src, int src_ld, int src_coff,
                             int rows,
                             unsigned short* __restrict__ dhi, unsigned short* __restrict__ dlo,
                             int dst_ld, int dst_coff)
{
  int n = rows << 9;
  for (int i = blockIdx.x*blockDim.x + threadIdx.x; i < n; i += gridDim.x*blockDim.x){
    int r = i >> 9, c = i & 511;
    float x = src[(size_t)r*src_ld + src_coff + c];
    unsigned short h = f_to_bf16(x);
    dhi[(size_t)r*dst_ld + dst_coff + c] = h;
    if (dlo) dlo[(size_t)r*dst_ld + dst_coff + c] = f_to_bf16(x - bf16_to_f(h));
  }
}

// Embedding gather -> f32, row = b*T+t
__global__ void embed_kernel(const int* __restrict__ caps, const float* __restrict__ embW,
                             float* __restrict__ emb)
{
  int row = blockIdx.x;
  int cap = caps[row];
  const float4* s = (const float4*)(embW + (size_t)cap*E);
  float4* d = (float4*)(emb + (size_t)row*E);
  for (int e = threadIdx.x; e < E/4; e += blockDim.x) d[e] = s[e];
}

// mean over P, then h0/c0 = mean@W^T + b
__global__ __launch_bounds__(512) void prep_kernel(
    const float* __restrict__ feats,
    const float* __restrict__ inith_W, const float* __restrict__ inith_b,
    const float* __restrict__ initc_W, const float* __restrict__ initc_b,
    float* __restrict__ h_state, float* __restrict__ c_state)
{
  __shared__ float mf[E];
  const int b = blockIdx.x, tid = threadIdx.x;
  const float* fb = feats + (size_t)b*P*E + tid;
  float s = 0.f;
  for (int p = 0; p < P; ++p) s += fb[(size_t)p*E];
  mf[tid] = s * (1.0f/196.0f);
  __syncthreads();
  const float* wh = inith_W + (size_t)tid*E;
  const float* wc = initc_W + (size_t)tid*E;
  float h0 = inith_b[tid], c0 = initc_b[tid];
  #pragma unroll 4
  for (int e = 0; e < E; e += 4){
    float4 a4 = *(const float4*)(wh + e);
    float4 b4 = *(const float4*)(wc + e);
    float4 m4 = *(const float4*)(mf + e);
    h0 += dot4(a4, m4);
    c0 += dot4(b4, m4);
  }
  h_state[b*H + tid] = h0;
  c_state[b*H + tid] = c0;
}

// WhT[k][j] = attn_W[j][E + k]  (64x64 LDS tiles, coalesced both sides)
__global__ __launch_bounds__(256) void transpose_wh_kernel(
    const float* __restrict__ attn_W, float* __restrict__ WhT)
{
  __shared__ float tile[64][65];
  const int jt = blockIdx.x & 7, kt = blockIdx.x >> 3;
  const int tx = threadIdx.x & 63, ty = threadIdx.x >> 6;
  for (int r = ty; r < 64; r += 4)
    tile[r][tx] = attn_W[(size_t)(jt*64 + r)*(E+H) + E + kt*64 + tx];
  __syncthreads();
  for (int r = ty; r < 64; r += 4)
    WhT[(size_t)(kt*64 + r)*512 + jt*64 + tx] = tile[tx][r];
}

// ---------------------------------------------------------------------------
// m97-style bf16 GEMM: C = sum_passes A_p (MxK) * B_p(NxK)^T [+bias]
__global__ __launch_bounds__(256) void gemm_bt_kernel(
    const unsigned short* __restrict__ A0, const unsigned short* __restrict__ A1,
    const unsigned short* __restrict__ A2,
    const unsigned short* __restrict__ B0, const unsigned short* __restrict__ B1,
    const unsigned short* __restrict__ B2,
    float* __restrict__ Cc, const float* __restrict__ bias,
    int N, int K, int npasses, int mt, int swz)
{
  __shared__ __align__(16) unsigned short Al[128*32];
  __shared__ __align__(16) unsigned short Bl[128*32];
  const int tid = threadIdx.x;
  const int wid = tid >> 6, l = tid & 63;
  int f = blockIdx.x;
  if (swz) f = (f & 7)*((int)gridDim.x >> 3) + (f >> 3);
  const int m0 = (f % mt)*128, n0 = (f / mt)*128;
  const int wr = wid >> 1, wc = wid & 1;

  f4v acc[4][4];
  #pragma unroll
  for (int i = 0; i < 4; ++i)
    #pragma unroll
    for (int j = 0; j < 4; ++j) acc[i][j] = (f4v){0.f,0.f,0.f,0.f};

  const int s0 = tid, s1 = tid + 256;
  const int r0 = s0 >> 2, g0 = (s0 & 3) ^ ((r0 >> 1) & 3);
  const int r1 = s1 >> 2, g1 = (s1 & 3) ^ ((r1 >> 1) & 3);
  const int la = l & 15, ch = l >> 4;

  for (int pass = 0; pass < npasses; ++pass){
    const unsigned short* Ap = pass == 0 ? A0 : (pass == 1 ? A1 : A2);
    const unsigned short* Bp = pass == 0 ? B0 : (pass == 1 ? B1 : B2);
    for (int k0 = 0; k0 < K; k0 += 32){
      __syncthreads();
      load_lds16(Ap + (size_t)(m0 + r0)*K + k0 + g0*8, Al + s0*8);
      load_lds16(Ap + (size_t)(m0 + r1)*K + k0 + g1*8, Al + s1*8);
      load_lds16(Bp + (size_t)(n0 + r0)*K + k0 + g0*8, Bl + s0*8);
      load_lds16(Bp + (size_t)(n0 + r1)*K + k0 + g1*8, Bl + s1*8);
      __syncthreads();
      s8v av[4], bv[4];
      #pragma unroll
      for (int mi = 0; mi < 4; ++mi){
        int row = wr*64 + mi*16 + la;
        int cs = ch ^ ((row >> 1) & 3);
        av[mi] = *(const s8v*)(Al + (row*4 + cs)*8);
      }
      #pragma unroll
      for (int ni = 0; ni < 4; ++ni){
        int row = wc*64 + ni*16 + la;
        int cs = ch ^ ((row >> 1) & 3);
        bv[ni] = *(const s8v*)(Bl + (row*4 + cs)*8);
      }
      #pragma unroll
      for (int mi = 0; mi < 4; ++mi)
        #pragma unroll
        for (int ni = 0; ni < 4; ++ni)
          acc[mi][ni] = __builtin_amdgcn_mfma_f32_16x16x32_bf16(av[mi], bv[ni], acc[mi][ni], 0, 0, 0);
    }
  }
  #pragma unroll
  for (int mi = 0; mi < 4; ++mi){
    int row = m0 + wr*64 + mi*16 + (l >> 4)*4;
    #pragma unroll
    for (int ni = 0; ni < 4; ++ni){
      int col = n0 + wc*64 + ni*16 + (l & 15);
      float bb = bias ? bias[col] : 0.0f;
      #pragma unroll
      for (int r = 0; r < 4; ++r)
        Cc[(size_t)(row + r)*N + col] = acc[mi][ni][r] + bb;
    }
  }
}

// ---------------------------------------------------------------------------
// Persistent loop kernel. blk -> (b = blk&31, sub = blk>>5) for attention
// phases; blk owns j-pair {2blk, 2blk+1} x 4 gates for LSTM (weights in LDS).
// Step-invariant feat_proj/features slices are parked in LDS (fpl f32 /
// ftl bf16) so phases B/C touch no global memory.
// Per step: [A+B fused] -mini(8)- [C] -grid- [D] -grid-.
__global__ __launch_bounds__(512, 1) void loop_kernel(
    const float* __restrict__ feats, const float* __restrict__ feat_proj,
    const float* __restrict__ WhT, const float* __restrict__ attn_b,
    const float* __restrict__ v_w, const float* __restrict__ emb,
    const float* __restrict__ W_ih, const float* __restrict__ W_hh,
    const float* __restrict__ b_ih, const float* __restrict__ b_hh,
    float* __restrict__ hbuf0, float* __restrict__ hbuf1,
    const float* __restrict__ c_init,
    float* __restrict__ ctx_g, float* __restrict__ s_part,
    unsigned short* __restrict__ hall_h, unsigned short* __restrict__ hall_l,
    unsigned* __restrict__ fm, unsigned* __restrict__ fg1, unsigned* __restrict__ fg2)
{
  __shared__ float Wl[8][1540];            // 49.3KB gate weights [Wih|Whh]
  __shared__ float fpl[P*64];              // 50.2KB feat_proj[b,:,sub-slice] f32
  __shared__ unsigned short ftl[P*64];     // 25.1KB features[b,:,sub-slice] bf16
  __shared__ float hs[512];
  __shared__ float hwl[64];
  __shared__ float partA[8][72];
  __shared__ float scr[1024];
  __shared__ float aux[256];
  __shared__ float bias8[8];
  __shared__ float smx, sinv;

  const int blk = blockIdx.x, tid = threadIdx.x;
  const int b = blk & 31, sub = blk >> 5;
  const int jb = blk*2;
  const int l = tid & 63, wv = tid >> 6;

  // ---- prologue: park gate weights + attention slices in LDS ----
  #pragma unroll
  for (int r = 0; r < 8; ++r){
    const int col = (r >> 1)*512 + jb + (r & 1);
    const float4* wi = (const float4*)(W_ih + (size_t)col*1024);
    const float4* wh = (const float4*)(W_hh + (size_t)col*512);
    float4* d0 = (float4*)&Wl[r][0];
    float4* d1 = (float4*)&Wl[r][1024];
    for (int q = tid; q < 256; q += NT) d0[q] = wi[q];
    for (int q = tid; q < 128; q += NT) d1[q] = wh[q];
  }
  for (int i = tid; i < P*64; i += NT){
    const int p = i >> 6, c = i & 63;
    const size_t g = ((size_t)b*P + p)*512 + sub*64 + c;
    fpl[i] = feat_proj[g];
    ftl[i] = f_to_bf16(feats[g]);
  }
  if (tid < 8){
    const int col = (tid >> 1)*512 + jb + (tid & 1);
    bias8[tid] = b_ih[col] + b_hh[col];
  }
  const float vl = v_w[sub*64 + l];
  const float ab = (tid < 64) ? attn_b[sub*64 + tid] : 0.f;
  float c_reg = 0.f;
  if (tid < 64) c_reg = c_init[(tid >> 1)*512 + jb + (tid & 1)];
  __syncthreads();

  for (int t = 0; t < T; ++t){
    const float* h_in  = (t & 1) ? hbuf1 : hbuf0;
    float*       h_out = (t & 1) ? hbuf0 : hbuf1;
    const unsigned gen = (unsigned)(t + 1);

    // ---- A: hWh[b][sub*64..+64) into LDS (coalesced WhT, broadcast h) ----
    hs[tid] = h_in[b*512 + tid];
    __syncthreads();
    {
      const float* wt = WhT + (size_t)(wv*64)*512 + sub*64 + l;
      const float* hk = hs + wv*64;
      float a = 0.f;
      #pragma unroll 8
      for (int kk = 0; kk < 64; ++kk) a += hk[kk] * wt[(size_t)kk*512];
      partA[wv][l] = a;
    }
    __syncthreads();
    if (tid < 64){
      float s = ab;
      #pragma unroll
      for (int k = 0; k < 8; ++k) s += partA[k][tid];
      hwl[tid] = s;
    }
    __syncthreads();

    // ---- B: partial scores over own j-slice (all operands in LDS) ----
    {
      const float hj = hwl[l];
      for (int p = wv; p < P; p += 8){
        float e2 = vl * fast_tanh(fpl[p*64 + l] + hj);
        #pragma unroll
        for (int off = 32; off; off >>= 1) e2 += __shfl_xor(e2, off);
        if (l == 0) s_part[((size_t)b*P + p)*8 + sub] = e2;
      }
    }
    bar_flag(fm + b*8 + sub, fm + b*8, 8, gen);

    // ---- C: reduce partials -> softmax -> ctx slice (feats from LDS) ----
    {
      float sc_v = -1e30f;
      if (tid < P){
        const float* sp = s_part + ((size_t)b*P + tid)*8;
        float4 q0 = *(const float4*)sp, q1 = *(const float4*)(sp + 4);
        sc_v = (q0.x + q0.y + q0.z + q0.w) + (q1.x + q1.y + q1.z + q1.w);
      }
      if (tid < 256) aux[tid] = sc_v;
      __syncthreads();
      if (tid < 64){
        float m = -1e30f;
        #pragma unroll
        for (int i = 0; i < 4; ++i) m = fmaxf(m, aux[tid + i*64]);
        #pragma unroll
        for (int off = 32; off; off >>= 1) m = fmaxf(m, __shfl_xor(m, off));
        if (tid == 0) smx = m;
      }
      __syncthreads();
      float al = (tid < P) ? __expf(sc_v - smx) : 0.f;
      if (tid < 256) aux[tid] = al;
      __syncthreads();
      if (tid < 64){
        float s = 0.f;
        #pragma unroll
        for (int i = 0; i < 4; ++i) s += aux[tid + i*64];
        #pragma unroll
        for (int off = 32; off; off >>= 1) s += __shfl_xor(s, off);
        if (tid == 0) sinv = 1.0f/s;
      }
      __syncthreads();
      float a = 0.f;
      for (int p = wv; p < P; p += 8)
        a += aux[p] * bf16_to_f(ftl[p*64 + l]);
      partA[wv][l] = a;
      __syncthreads();
      if (tid < 64){
        float s = 0.f;
        #pragma unroll
        for (int k = 0; k < 8; ++k) s += partA[k][tid];
        ctx_g[b*512 + sub*64 + tid] = s * sinv;
      }
    }
    bar_flag(fg1 + blk, fg1, NB, gen);

    // ---- D: gates for j in {jb, jb+1} x 4 gates, all 32 batches ----
    {
      const int kh = tid >> 8, o = tid & 255, bb = o >> 3, c = o & 7;
      const float* wrow = &Wl[c][kh*768];
      float a = 0.f;
      if (kh == 0){
        const float4* xe = (const float4*)(emb + ((size_t)bb*T + t)*512);
        const float4* wvp = (const float4*)wrow;
        #pragma unroll 8
        for (int i = 0; i < 128; ++i) a += dot4(wvp[i], xe[i]);
        const float4* xc = (const float4*)(ctx_g + bb*512);
        const float4* wv2 = (const float4*)(wrow + 512);
        #pragma unroll 8
        for (int i = 0; i < 64; ++i) a += dot4(wv2[i], xc[i]);
      } else {
        const float4* xc = (const float4*)(ctx_g + bb*512 + 256);
        const float4* wvp = (const float4*)wrow;
        #pragma unroll 8
        for (int i = 0; i < 64; ++i) a += dot4(wvp[i], xc[i]);
        const float4* xh = (const float4*)(h_in + bb*512);
        const float4* wv2 = (const float4*)(wrow + 256);
        #pragma unroll 8
        for (int i = 0; i < 128; ++i) a += dot4(wv2[i], xh[i]);
      }
      scr[kh*256 + o] = a;
    }
    __syncthreads();
    if (tid < 256) scr[512 + tid] = scr[tid] + scr[256 + tid];
    __syncthreads();
    if (tid < 64){
      const int bb = tid >> 1, jj = tid & 1;
      float gv[4];
      #pragma unroll
      for (int g = 0; g < 4; ++g)
        gv[g] = scr[512 + bb*8 + g*2 + jj] + bias8[g*2 + jj];
      const float i_ = sigmoidf_(gv[0]);
      const float f_ = sigmoidf_(gv[1]);
      const float g_ = fast_tanh(gv[2]);
      const float o_ = sigmoidf_(gv[3]);
      const int j = jb + jj;
      const float c_new = f_*c_reg + i_*g_;
      const float h_new = o_*fast_tanh(c_new);
      c_reg = c_new;
      h_out[bb*512 + j] = h_new;
      const unsigned short hh = f_to_bf16(h_new);
      hall_h[((size_t)bb*T + t)*512 + j] = hh;
      hall_l[((size_t)bb*T + t)*512 + j] = f_to_bf16(h_new - bf16_to_f(hh));
    }
    bar_flag(fg2 + blk, fg2, NB, gen);
  }
}

// ---------------------------------------------------------------------------
extern "C" void kernel_launch(void* const* d_in, const int* in_sizes, int n_in,
                              void* d_out, int out_size, void* d_ws, size_t ws_size,
                              hipStream_t stream)
{
  (void)in_sizes; (void)n_in; (void)out_size;
  const float* features = (const float*)d_in[0];
  const int*   captions = (const int*)d_in[1];
  const float* embed_W  = (const float*)d_in[2];
  const float* attn_W   = (const float*)d_in[3];
  const float* attn_b   = (const float*)d_in[4];
  const float* v_w      = (const float*)d_in[5];
  const float* W_ih     = (const float*)d_in[6];
  const float* W_hh     = (const float*)d_in[7];
  const float* b_ih     = (const float*)d_in[8];
  const float* b_hh     = (const float*)d_in[9];
  const float* lin_W    = (const float*)d_in[10];
  const float* lin_b    = (const float*)d_in[11];
  const float* inith_W  = (const float*)d_in[12];
  const float* inith_b  = (const float*)d_in[13];
  const float* initc_W  = (const float*)d_in[14];
  const float* initc_b  = (const float*)d_in[15];

  // "early" scratch in d_out (dead before final logits GEMM writes d_out)
  char* o = (char*)d_out;
  unsigned short* feat_bf   = (unsigned short*)o; o += (size_t)(B*P)*E*2;   // 6.4MB
  unsigned short* Wf_bf     = (unsigned short*)o; o += (size_t)H*E*2;       // 0.5MB
  float*          feat_proj = (float*)o;          o += (size_t)(B*P)*H*4;   // 12.9MB

  // persistent scratch in d_ws
  const size_t SZ_LIN  = (size_t)V*H*2;          // 32.77MB
  const size_t SZ_HALL = (size_t)(B*T)*H*2;      // 1MB
  const size_t SZ_EMB  = (size_t)(B*T)*E*4;      // 2.1MB
  const size_t SZ_ST   = (size_t)B*H*4;          // 64KB
  const size_t SZ_WHT  = (size_t)H*H*4;          // 1MB
  const size_t SZ_SP   = (size_t)B*P*8*4;        // 0.2MB
  const size_t SZ_FLG  = 4096;
  const size_t need_wo = SZ_LIN + 2*SZ_HALL + SZ_EMB + 5*SZ_ST + SZ_WHT + SZ_SP + SZ_FLG;
  const bool three = (ws_size >= need_wo + SZ_LIN);

  char* w = (char*)d_ws;
  unsigned short* lin_hi  = (unsigned short*)w; w += SZ_LIN;
  unsigned short* lin_lo  = (unsigned short*)w; if (three) w += SZ_LIN;
  unsigned short* hall_hi = (unsigned short*)w; w += SZ_HALL;
  unsigned short* hall_lo = (unsigned short*)w; w += SZ_HALL;
  float*          emb_ws  = (float*)w;          w += SZ_EMB;
  float*          hbuf0   = (float*)w;          w += SZ_ST;
  float*          hbuf1   = (float*)w;          w += SZ_ST;
  float*          c_state = (float*)w;          w += SZ_ST;
  float*          ctx_ws  = (float*)w;          w += SZ_ST;
  float*          WhT_ws  = (float*)w;          w += SZ_WHT;
  float*          spart   = (float*)w;          w += SZ_SP;
  unsigned*       flags   = (unsigned*)w;       w += SZ_FLG;
  unsigned* fm  = flags;          // [256] mini-barrier flags [b*8+sub]
  unsigned* fg1 = flags + 256;    // [256] grid barrier 1
  unsigned* fg2 = flags + 512;    // [256] grid barrier 2

  // --- conversions / gathers / init ---
  split_kernel<<<2048, 256, 0, stream>>>(features, E, 0, B*P, feat_bf, nullptr, E, 0);
  split_kernel<<<256, 256, 0, stream>>>(attn_W, E+H, 0, H, Wf_bf, nullptr, E, 0);
  split_kernel<<<2048, 256, 0, stream>>>(lin_W, 512, 0, V, lin_hi, three ? lin_lo : nullptr, 512, 0);
  embed_kernel<<<B*T, 128, 0, stream>>>(captions, embed_W, emb_ws);
  prep_kernel<<<B, 512, 0, stream>>>(features, inith_W, inith_b, initc_W, initc_b,
                                     hbuf0, c_state);
  transpose_wh_kernel<<<64, 256, 0, stream>>>(attn_W, WhT_ws);
  hipMemsetAsync(flags, 0, SZ_FLG, stream);

  // feat_proj = features @ Wf^T (bf16 1-pass; error damped through tanh/softmax)
  gemm_bt_kernel<<<(B*P/128)*(E/128), 256, 0, stream>>>(
      feat_bf, feat_bf, feat_bf, Wf_bf, Wf_bf, Wf_bf,
      feat_proj, nullptr, E, E, 1, B*P/128, 0);

  // --- the whole recurrence in one persistent kernel ---
  loop_kernel<<<NB, NT, 0, stream>>>(
      features, feat_proj, WhT_ws, attn_b, v_w, emb_ws, W_ih, W_hh, b_ih, b_hh,
      hbuf0, hbuf1, c_state, ctx_ws, spart, hall_hi, hall_lo, fm, fg1, fg2);

  // --- logits = h_all @ lin_W^T + lin_b (bf16x3, XCD-swizzled grid) ---
  gemm_bt_kernel<<<(V/128)*(B*T/128), 256, 0, stream>>>(
      hall_hi, hall_lo, hall_hi, lin_hi, lin_hi, three ? lin_lo : lin_hi,
      (float*)d_out, lin_b, V, H, three ? 3 : 2, B*T/128, 1);
}